// Round 1
// 146.893 us; speedup vs baseline: 1.0060x; 1.0060x over previous
//
#include <hip/hip_runtime.h>

#define IN_H 1024
#define IN_W 1024
#define OUT_H 256
#define OUT_W 256
#define G 16                // output rows per block
#define ROWS (4*G + 12)     // 76 input rows touched per block (halo 1.1875x vs 1.375x at G=8)
#define GUARD_L 6
#define PITCH 1036          // 6 guard + 1024 data + 6 guard (multiple of 4 -> 16B-aligned rows)
#define HROWS 8             // rows staged in LDS per half (LDS stays at 33 KB)

// 16-tap antialiased bicubic weights for scale=0.25 (exact dyadic values,
// identical for every output position; sum == 1.0 exactly).
// W[j] = 0.25 * cubic((7.5 - j) * 0.25)
__constant__ float WTAP[16] = {
    -0.001708984375f, -0.010986328125f, -0.018310546875f, -0.011962890625f,
     0.022705078125f,  0.097412109375f,  0.181884765625f,  0.240966796875f,
     0.240966796875f,  0.181884765625f,  0.097412109375f,  0.022705078125f,
    -0.011962890625f, -0.018310546875f, -0.010986328125f, -0.001708984375f
};

__global__ __launch_bounds__(256, 2)
void bicubic_fused_kernel(const float* __restrict__ in, float* __restrict__ out) {
    const int t = threadIdx.x;              // 0..255

    // XCD-chunked swizzle: grid = 384 (384 % 8 == 0 -> bijective).
    // HW round-robins blockIdx across 8 XCDs; this remap gives XCD x the
    // contiguous chunk [48x, 48x+48) = 3 whole images, so og-neighbor blocks
    // (sharing 12 halo rows) hit the same 4 MiB per-XCD L2 (== 1 channel image).
    const int b   = blockIdx.x;
    const int per = gridDim.x >> 3;         // 48
    const int swz = (b & 7) * per + (b >> 3);

    const int bc  = swz / (OUT_H / G);      // image*channel index 0..23
    const int og  = swz % (OUT_H / G);      // output-row group 0..15
    const int oh0 = og * G;

    // Each LDS row: word index = x + GUARD_L for x in [0,1024); guards hold
    // replicated border values so the horizontal 16-tap window for output t
    // is exactly words [4t, 4t+16) -> four 16B-aligned float4 reads.
    __shared__ float vrow[HROWS][PITCH];    // 8*1036*4 = 33 KB

    const float* src = in + (size_t)bc * (IN_H * IN_W);

    // ---- vertical pass: 16-tap decimating conv along H, float4 per thread ----
    float4 acc[G];
#pragma unroll
    for (int i = 0; i < G; ++i) acc[i] = make_float4(0.f, 0.f, 0.f, 0.f);

#pragma unroll
    for (int r = 0; r < ROWS; ++r) {
        int y = oh0 * 4 + r - 6;
        y = min(max(y, 0), IN_H - 1);  // border replication
        const float4 v = *(const float4*)(src + (size_t)y * IN_W + 4 * t);
#pragma unroll
        for (int i = 0; i < G; ++i) {
            const int j = r - 4 * i;   // compile-time after unroll
            if (j >= 0 && j < 16) {
                const float w = WTAP[j];
                acc[i].x = fmaf(w, v.x, acc[i].x);
                acc[i].y = fmaf(w, v.y, acc[i].y);
                acc[i].z = fmaf(w, v.z, acc[i].z);
                acc[i].w = fmaf(w, v.w, acc[i].w);
            }
        }
    }

    // ---- horizontal pass in two 8-row stages reusing one LDS buffer ----
#pragma unroll
    for (int h = 0; h < 2; ++h) {
        if (h) __syncthreads();        // WAR: previous half's reads must drain

        // stage vertical results to LDS (main data at word 6+4t: 8B-aligned float2 pair)
#pragma unroll
        for (int k = 0; k < HROWS; ++k) {
            const int i = h * HROWS + k;
            float2* p = (float2*)&vrow[k][GUARD_L + 4 * t];
            p[0] = make_float2(acc[i].x, acc[i].y);
            p[1] = make_float2(acc[i].z, acc[i].w);
        }
        if (t == 0) {
#pragma unroll
            for (int k = 0; k < HROWS; ++k)
                for (int g = 0; g < GUARD_L; ++g)
                    vrow[k][g] = acc[h * HROWS + k].x;            // x<0 -> v[0]
        }
        if (t == 255) {
#pragma unroll
            for (int k = 0; k < HROWS; ++k)
                for (int g = GUARD_L + IN_W; g < PITCH; ++g)
                    vrow[k][g] = acc[h * HROWS + k].w;            // x>1023 -> v[1023]
        }
        __syncthreads();

        // 4 aligned float4 LDS reads + 16 FMAs per output
#pragma unroll
        for (int k = 0; k < HROWS; ++k) {
            const float4* q = (const float4*)&vrow[k][4 * t];  // 16B-aligned
            float s = 0.f;
#pragma unroll
            for (int m = 0; m < 4; ++m) {
                const float4 v = q[m];
                s = fmaf(WTAP[4 * m + 0], v.x, s);
                s = fmaf(WTAP[4 * m + 1], v.y, s);
                s = fmaf(WTAP[4 * m + 2], v.z, s);
                s = fmaf(WTAP[4 * m + 3], v.w, s);
            }
            out[((size_t)bc * OUT_H + oh0 + h * HROWS + k) * OUT_W + t] = s;
        }
    }
}

extern "C" void kernel_launch(void* const* d_in, const int* in_sizes, int n_in,
                              void* d_out, int out_size, void* d_ws, size_t ws_size,
                              hipStream_t stream) {
    const float* in = (const float*)d_in[0];
    float* out = (float*)d_out;
    const int nbc = in_sizes[0] / (IN_H * IN_W);   // 8*3 = 24
    dim3 grid(nbc * (OUT_H / G));                  // 24 * 16 = 384 blocks
    dim3 block(256);
    bicubic_fused_kernel<<<grid, block, 0, stream>>>(in, out);
}

// Round 2
// 145.975 us; speedup vs baseline: 1.0124x; 1.0063x over previous
//
#include <hip/hip_runtime.h>

#define IN_H 1024
#define IN_W 1024
#define OUT_H 256
#define OUT_W 256
#define G 8                 // output rows per block -> grid 768 = 3*256: perfectly balanced rounds
#define ROWS (4*G + 12)     // 44 input rows touched per block
#define GUARD_L 6
#define PITCH 1040          // 6 guard + 1024 data + 10 guard (multiple of 4 -> aligned rows)

// 16-tap antialiased bicubic weights for scale=0.25 (exact dyadic values,
// identical for every output position; sum == 1.0 exactly).
// W[j] = 0.25 * cubic((7.5 - j) * 0.25)
__constant__ float WTAP[16] = {
    -0.001708984375f, -0.010986328125f, -0.018310546875f, -0.011962890625f,
     0.022705078125f,  0.097412109375f,  0.181884765625f,  0.240966796875f,
     0.240966796875f,  0.181884765625f,  0.097412109375f,  0.022705078125f,
    -0.011962890625f, -0.018310546875f, -0.010986328125f, -0.001708984375f
};

__global__ __launch_bounds__(256, 4)   // 4 blocks/CU: 133 KB LDS of 160, 16 waves for latency hiding
void bicubic_fused_kernel(const float* __restrict__ in, float* __restrict__ out) {
    const int t = threadIdx.x;              // 0..255

    // XCD-chunked swizzle: grid = 768 (768 % 8 == 0 -> bijective).
    // HW round-robins blockIdx across the 8 XCDs; this remap hands XCD x the
    // contiguous chunk [96x, 96x+96) = 3 whole channel-images. The 32 og-blocks
    // of one image run concurrently on that XCD's 32 CUs, so the 12 halo rows
    // shared by og-neighbors are fetched once into the 4 MiB per-XCD L2 and
    // re-read as L2 hits instead of going back to LLC/HBM.
    const int b   = blockIdx.x;
    const int per = gridDim.x >> 3;         // 96
    const int swz = (b & 7) * per + (b >> 3);

    const int bc  = swz / (OUT_H / G);      // image*channel index 0..23
    const int og  = swz % (OUT_H / G);      // output-row group 0..31
    const int oh0 = og * G;

    // Each LDS row: word index = x + GUARD_L for x in [0,1024); guards hold
    // replicated border values so the horizontal 16-tap window for output t
    // is exactly words [4t, 4t+16) -> four 16B-aligned float4 reads.
    __shared__ float vrow[G][PITCH];        // 8*1040*4 = 33.3 KB

    const float* src = in + (size_t)bc * (IN_H * IN_W);

    // ---- vertical pass: 16-tap decimating conv along H, float4 per thread ----
    float4 acc[G];
#pragma unroll
    for (int i = 0; i < G; ++i) acc[i] = make_float4(0.f, 0.f, 0.f, 0.f);

#pragma unroll
    for (int r = 0; r < ROWS; ++r) {
        int y = oh0 * 4 + r - 6;
        y = min(max(y, 0), IN_H - 1);  // border replication
        const float4 v = *(const float4*)(src + (size_t)y * IN_W + 4 * t);
#pragma unroll
        for (int i = 0; i < G; ++i) {
            const int j = r - 4 * i;   // compile-time after unroll
            if (j >= 0 && j < 16) {
                const float w = WTAP[j];
                acc[i].x = fmaf(w, v.x, acc[i].x);
                acc[i].y = fmaf(w, v.y, acc[i].y);
                acc[i].z = fmaf(w, v.z, acc[i].z);
                acc[i].w = fmaf(w, v.w, acc[i].w);
            }
        }
    }

    // stage vertical results to LDS (main data at word 6+4t: 8B-aligned float2 pair)
#pragma unroll
    for (int i = 0; i < G; ++i) {
        float2* p = (float2*)&vrow[i][GUARD_L + 4 * t];
        p[0] = make_float2(acc[i].x, acc[i].y);
        p[1] = make_float2(acc[i].z, acc[i].w);
    }
    if (t == 0) {
#pragma unroll
        for (int i = 0; i < G; ++i)
            for (int k = 0; k < GUARD_L; ++k) vrow[i][k] = acc[i].x;   // x<0 -> v[0]
    }
    if (t == 255) {
#pragma unroll
        for (int i = 0; i < G; ++i)
            for (int k = GUARD_L + IN_W; k < PITCH; ++k) vrow[i][k] = acc[i].w; // x>1023 -> v[1023]
    }
    __syncthreads();

    // ---- horizontal pass: 4 aligned float4 LDS reads + 16 FMAs per output ----
#pragma unroll
    for (int i = 0; i < G; ++i) {
        const float4* q = (const float4*)&vrow[i][4 * t];  // 16B-aligned
        float s = 0.f;
#pragma unroll
        for (int k = 0; k < 4; ++k) {
            const float4 v = q[k];
            s = fmaf(WTAP[4 * k + 0], v.x, s);
            s = fmaf(WTAP[4 * k + 1], v.y, s);
            s = fmaf(WTAP[4 * k + 2], v.z, s);
            s = fmaf(WTAP[4 * k + 3], v.w, s);
        }
        out[((size_t)bc * OUT_H + oh0 + i) * OUT_W + t] = s;
    }
}

extern "C" void kernel_launch(void* const* d_in, const int* in_sizes, int n_in,
                              void* d_out, int out_size, void* d_ws, size_t ws_size,
                              hipStream_t stream) {
    const float* in = (const float*)d_in[0];
    float* out = (float*)d_out;
    const int nbc = in_sizes[0] / (IN_H * IN_W);   // 8*3 = 24
    dim3 grid(nbc * (OUT_H / G));                  // 24 * 32 = 768 blocks
    dim3 block(256);
    bicubic_fused_kernel<<<grid, block, 0, stream>>>(in, out);
}